// Round 1
// baseline (3136.624 us; speedup 1.0000x reference)
//
#include <hip/hip_runtime.h>
#include <hip/hip_bf16.h>

typedef _Float16 f16;
typedef _Float16 half8 __attribute__((ext_vector_type(8)));
typedef float f32x4 __attribute__((ext_vector_type(4)));

#define S_LEN 1024
#define DMODEL 512
#define NFFT   2048
#define FPAD   1056     // padded f-slots per batch (1025 valid)
#define RPB    2112     // rows per batch = 2*FPAD (re/im interleaved)
#define RTOT   4224     // 2 batches
#define CPS    1064     // cpcm f-stride (padded, zeros past 1024)
#define NROW   2048     // B*S

__device__ __forceinline__ float2 mkf2(float a, float b) { float2 r; r.x = a; r.y = b; return r; }

// ---------------- FFT-2048 in LDS (radix-2 DIT, bit-reversed input) ----------------
template<bool INV>
__device__ __forceinline__ void fft2048(float2* z, const float2* __restrict__ tw, int tid) {
  for (int i = tid; i < 2048; i += 256) {
    int j = (int)(__brev((unsigned)i) >> 21);
    if (i < j) { float2 a = z[i]; z[i] = z[j]; z[j] = a; }
  }
  __syncthreads();
  for (int sl = 1; sl <= 11; ++sl) {
    int hlf = 1 << (sl - 1);
    for (int idx = tid; idx < 1024; idx += 256) {
      int j = idx & (hlf - 1);
      int base = (idx >> (sl - 1)) << sl;
      float2 wv = tw[j << (11 - sl)];
      if (INV) wv.y = -wv.y;
      float2 a = z[base + j];
      float2 b = z[base + j + hlf];
      float tr = b.x * wv.x - b.y * wv.y;
      float ti = b.x * wv.y + b.y * wv.x;
      z[base + j]       = mkf2(a.x + tr, a.y + ti);
      z[base + j + hlf] = mkf2(a.x - tr, a.y - ti);
    }
    __syncthreads();
  }
}

// ---------------- init kernels ----------------
__global__ void k_twiddle(float2* tw) {
  int i = blockIdx.x * 256 + threadIdx.x;
  if (i < 1024) {
    float ang = -6.2831853071795864769f * (float)i / 2048.0f;
    tw[i] = mkf2(cosf(ang), sinf(ang));   // exp(-2*pi*i*m/2048)
  }
}

// rfft of phi columns (pairs packed into one complex FFT)
__global__ void k_fft_phi(const float* __restrict__ phi, float2* __restrict__ Vf,
                          const float2* __restrict__ tw) {
  __shared__ float2 z[2048];
  int tid = threadIdx.x;
  int k0 = blockIdx.x * 2;
  for (int t = tid; t < 1024; t += 256) {
    float2 v = *(const float2*)(phi + (size_t)t * 16 + k0);
    z[t] = v;
  }
  for (int t = 1024 + tid; t < 2048; t += 256) z[t] = mkf2(0.f, 0.f);
  __syncthreads();
  fft2048<false>(z, tw, tid);
  for (int f = tid; f <= 1024; f += 256) {
    float2 zf = z[f], zc = z[(2048 - f) & 2047];
    Vf[(size_t)k0 * 1025 + f]       = mkf2(0.5f * (zf.x + zc.x), 0.5f * (zf.y - zc.y));
    Vf[(size_t)(k0 + 1) * 1025 + f] = mkf2(0.5f * (zf.y + zc.y), 0.5f * (zc.x - zf.x));
  }
}

// cpcm[kb][f] = sig4[k] * Vf_eff / 2048 ; kb<16: plus (Vf), kb>=16: minus (freq-shifted Vf)
__global__ void k_cpcm(const float2* __restrict__ Vf, const float* __restrict__ sigma,
                       float2* __restrict__ cpcm) {
  int idx = blockIdx.x * 256 + threadIdx.x;
  if (idx >= 32 * CPS) return;
  int kb = idx / CPS, f = idx - kb * CPS;
  float2 v = mkf2(0.f, 0.f);
  if (f <= 1024) {
    int k = kb & 15;
    if (kb < 16) {
      v = Vf[(size_t)k * 1025 + f];
    } else {
      if (f == 0)         v = Vf[(size_t)k * 1025 + 1024];
      else if (f == 1024) v = Vf[(size_t)k * 1025];
      else { float2 t = Vf[(size_t)k * 1025 + (1024 - f)]; v = mkf2(t.x, -t.y); }
    }
    float s = powf(sigma[k], 0.25f) * (1.0f / 2048.0f);
    v.x *= s; v.y *= s;
  }
  cpcm[idx] = v;
}

// ---------------- per-layer weight cast/transpose ----------------
__global__ void k_cast(const float* __restrict__ mp, const float* __restrict__ mm,
                       const float* __restrict__ mu, const float* __restrict__ fc1,
                       const float* __restrict__ fc2,
                       f16* __restrict__ Wsp, f16* __restrict__ Wu,
                       f16* __restrict__ Wf1, f16* __restrict__ Wf2) {
  __shared__ float T[64][65];
  int blk = blockIdx.x, tid = threadIdx.x;
  if (blk < 2048) {                    // Wsp: Wsp[(kb*512+o)][d] = m?[k][d][o]
    int mat = blk >> 6, tile = blk & 63;
    int d0 = (tile >> 3) * 64, o0 = (tile & 7) * 64;
    const float* src = (mat < 16) ? (mp + (size_t)mat * 262144)
                                  : (mm + (size_t)(mat - 16) * 262144);
    for (int q = tid; q < 4096; q += 256) {
      int i = q >> 6, j = q & 63;
      T[i][j] = src[(size_t)(d0 + i) * 512 + o0 + j];
    }
    __syncthreads();
    for (int q = tid; q < 4096; q += 256) {
      int i = q >> 6, j = q & 63;
      Wsp[(size_t)(mat * 512 + o0 + i) * 512 + d0 + j] = (f16)T[j][i];
    }
  } else if (blk < 2240) {             // Wu: Wu[o][ip*512+d] = mu[2-ip][d][o]
    int q0 = blk - 2048;
    int ip = q0 >> 6, tile = q0 & 63;
    int d0 = (tile >> 3) * 64, o0 = (tile & 7) * 64;
    const float* src = mu + (size_t)(2 - ip) * 262144;
    for (int q = tid; q < 4096; q += 256) {
      int i = q >> 6, j = q & 63;
      T[i][j] = src[(size_t)(d0 + i) * 512 + o0 + j];
    }
    __syncthreads();
    for (int q = tid; q < 4096; q += 256) {
      int i = q >> 6, j = q & 63;
      Wu[(size_t)(o0 + i) * 1536 + ip * 512 + d0 + j] = (f16)T[j][i];
    }
  } else if (blk < 3264) {             // fc1 perm copy: row 2h = y-row h, 2h+1 = gate-row h
    int q0 = blk - 2240;
    size_t e = ((size_t)q0 * 256 + tid) * 8;
    int jj = (int)(e >> 9), col = (int)(e & 511);
    int srow = (jj & 1) ? (2048 + (jj >> 1)) : (jj >> 1);
    const float4* s = (const float4*)(fc1 + (size_t)srow * 512 + col);
    float4 a = s[0], b = s[1];
    union { f16 h[8]; uint4 u; } pk;
    pk.h[0] = (f16)a.x; pk.h[1] = (f16)a.y; pk.h[2] = (f16)a.z; pk.h[3] = (f16)a.w;
    pk.h[4] = (f16)b.x; pk.h[5] = (f16)b.y; pk.h[6] = (f16)b.z; pk.h[7] = (f16)b.w;
    *(uint4*)(Wf1 + (size_t)jj * 512 + col) = pk.u;
  } else {                             // fc2 straight copy (already [o][j])
    int q0 = blk - 3264;
    size_t e = ((size_t)q0 * 256 + tid) * 8;
    const float4* s = (const float4*)(fc2 + e);
    float4 a = s[0], b = s[1];
    union { f16 h[8]; uint4 u; } pk;
    pk.h[0] = (f16)a.x; pk.h[1] = (f16)a.y; pk.h[2] = (f16)a.z; pk.h[3] = (f16)a.w;
    pk.h[4] = (f16)b.x; pk.h[5] = (f16)b.y; pk.h[6] = (f16)b.z; pk.h[7] = (f16)b.w;
    *(uint4*)(Wf2 + e) = pk.u;
  }
}

// ---------------- rmsnorm ----------------
__global__ void k_rmsnorm(const float* __restrict__ x, const float* __restrict__ w,
                          float* __restrict__ h, f16* __restrict__ hb) {
  int tid = threadIdx.x, l = tid & 63, wv = tid >> 6;
  int r = blockIdx.x * 4 + wv;
  const float* xr = x + (size_t)r * 512;
  float v[8]; float ss = 0.f;
#pragma unroll
  for (int j = 0; j < 8; ++j) { v[j] = xr[j * 64 + l]; ss += v[j] * v[j]; }
#pragma unroll
  for (int o = 32; o; o >>= 1) ss += __shfl_xor(ss, o, 64);
  float rn = rsqrtf(ss * (1.f / 512.f) + 1e-5f);
#pragma unroll
  for (int j = 0; j < 8; ++j) {
    float hv = v[j] * rn * w[j * 64 + l];
    h[(size_t)r * 512 + j * 64 + l] = hv;
    hb[(size_t)r * 512 + j * 64 + l] = (f16)hv;
  }
}

// ---------------- forward FFT of h -> Xbf (fp16, rows (b, f, re/im)) ----------------
__global__ void k_fft_fwd(const float* __restrict__ h, f16* __restrict__ Xbf,
                          const float2* __restrict__ tw) {
  __shared__ float2 z[2048];
  __shared__ __align__(16) f16 Xst[RPB * 8];
  int tid = threadIdx.x;
  int b = blockIdx.x >> 6;
  int dg = (blockIdx.x & 63) * 8;
  for (int i = tid; i < 62 * 8; i += 256) Xst[(2050 + (i >> 3)) * 8 + (i & 7)] = (f16)0.f;
  for (int c4 = 0; c4 < 4; ++c4) {
    int d0 = dg + 2 * c4;
    __syncthreads();
    for (int t = tid; t < 1024; t += 256)
      z[t] = *(const float2*)(h + (size_t)(b * 1024 + t) * 512 + d0);
    for (int t = 1024 + tid; t < 2048; t += 256) z[t] = mkf2(0.f, 0.f);
    __syncthreads();
    fft2048<false>(z, tw, tid);
    for (int f = tid; f <= 1024; f += 256) {
      float2 zf = z[f], zc = z[(2048 - f) & 2047];
      float x0r = 0.5f * (zf.x + zc.x), x0i = 0.5f * (zf.y - zc.y);
      float x1r = 0.5f * (zf.y + zc.y), x1i = 0.5f * (zc.x - zf.x);
      Xst[(2 * f) * 8 + 2 * c4]         = (f16)x0r;
      Xst[(2 * f + 1) * 8 + 2 * c4]     = (f16)x0i;
      Xst[(2 * f) * 8 + 2 * c4 + 1]     = (f16)x1r;
      Xst[(2 * f + 1) * 8 + 2 * c4 + 1] = (f16)x1i;
    }
  }
  __syncthreads();
  for (int i = tid; i < RPB; i += 256)
    *(uint4*)(Xbf + (size_t)(b * RPB + i) * 512 + dg) = *(const uint4*)&Xst[i * 8];
}

// ---------------- inverse FFT: sum of 4 partials -> spec (time domain, first S) ----------------
__global__ void k_fft_inv(const float* __restrict__ P, float* __restrict__ spec,
                          const float2* __restrict__ tw) {
  __shared__ float2 z[2048];
  __shared__ __align__(16) float Sst[1024 * 8];
  int tid = threadIdx.x;
  int b = blockIdx.x >> 6;
  int og = (blockIdx.x & 63) * 8;
  for (int c4 = 0; c4 < 4; ++c4) {
    int o0 = og + 2 * c4;
    __syncthreads();
    for (int f = tid; f <= 1024; f += 256) {
      size_t base0 = (size_t)o0 * RTOT + (size_t)b * RPB + 2 * f;
      float2 s0 = mkf2(0.f, 0.f), s1 = mkf2(0.f, 0.f);
#pragma unroll
      for (int g = 0; g < 4; ++g) {
        const float* Pg = P + (size_t)g * 512 * RTOT;
        float2 a = *(const float2*)(Pg + base0);
        float2 c = *(const float2*)(Pg + base0 + RTOT);
        s0.x += a.x; s0.y += a.y; s1.x += c.x; s1.y += c.y;
      }
      z[f] = mkf2(s0.x - s1.y, s0.y + s1.x);
      if (f >= 1 && f <= 1023) z[2048 - f] = mkf2(s0.x + s1.y, s1.x - s0.y);
    }
    __syncthreads();
    fft2048<true>(z, tw, tid);
    for (int t = tid; t < 1024; t += 256) {
      Sst[t * 8 + 2 * c4]     = z[t].x;
      Sst[t * 8 + 2 * c4 + 1] = z[t].y;
    }
  }
  __syncthreads();
  for (int i = tid; i < 1024; i += 256) {
    float* dst = spec + (size_t)(b * 1024 + i) * 512 + og;
    *(float4*)dst       = *(const float4*)&Sst[i * 8];
    *(float4*)(dst + 4) = *(const float4*)&Sst[i * 8 + 4];
  }
}

// ---------------- unified MFMA GEMM (128x128 tile, BK=64, 4 waves) ----------------
// MODE 0: spectral  C-rows=(b,f,c) A=Xbf       C-cols=o  B=Wsp (kb loop, complex-scale fuse) -> P[bz]
// MODE 1: AR        C-rows=o       A=Wu_bt     C-cols=r  B=h window        -> x1 = x+spec+acc (+fp16)
// MODE 2: MLP1      C-rows=jj      A=fc1perm   C-cols=r  B=x1b             -> g1 = y*silu(gate) fp16
// MODE 3: MLP2      C-rows=o       A=fc2       C-cols=r  B=g1              -> x = x + x1 + acc
template<int MODE>
__device__ __forceinline__ void pref(const f16* __restrict__ A, const f16* __restrict__ B0,
                                     const f16* __restrict__ zbuf,
                                     int r0, int c0, int bz, int tid, int step,
                                     uint4 av[4], uint4 bv[4]) {
  constexpr int LDA = (MODE == 0) ? 512 : (MODE == 1) ? 1536 : (MODE == 2) ? 512 : 2048;
  const int kA = (MODE == 0) ? ((step & 7) * 64) : step * 64;
#pragma unroll
  for (int i = 0; i < 4; ++i) {
    int c = i * 256 + tid, row = c >> 3, kc = c & 7;
    av[i] = *(const uint4*)(A + (size_t)(r0 + row) * LDA + kA + kc * 8);
    const f16* src;
    if constexpr (MODE == 0) {
      int kb = bz * 8 + (step >> 3);
      src = B0 + (size_t)(kb * 512 + c0 + row) * 512 + (step & 7) * 64 + kc * 8;
    } else if constexpr (MODE == 1) {
      int ip = step >> 3;
      int d0 = (step & 7) * 64;
      int rr = c0 + row;
      int tt = (rr & 1023) + ip - 2;
      src = (tt >= 0) ? (B0 + (size_t)(rr + ip - 2) * 512 + d0 + kc * 8) : zbuf;
    } else {
      constexpr int LDB = (MODE == 2) ? 512 : 2048;
      src = B0 + (size_t)(c0 + row) * LDB + step * 64 + kc * 8;
    }
    bv[i] = *(const uint4*)src;
  }
}

__device__ __forceinline__ void mma_step(const f16* As, const f16* Bs, int l, int wr, int wc,
                                         f32x4 acc[4][4]) {
  const int lr = l & 15, lg = (l >> 4) * 8;
#pragma unroll
  for (int kk = 0; kk < 64; kk += 32) {
    half8 af[4], bf[4];
#pragma unroll
    for (int m = 0; m < 4; ++m)
      af[m] = *(const half8*)(As + (wr * 64 + m * 16 + lr) * 72 + kk + lg);
#pragma unroll
    for (int n = 0; n < 4; ++n)
      bf[n] = *(const half8*)(Bs + (wc * 64 + n * 16 + lr) * 72 + kk + lg);
#pragma unroll
    for (int m = 0; m < 4; ++m)
#pragma unroll
      for (int n = 0; n < 4; ++n)
        acc[m][n] = __builtin_amdgcn_mfma_f32_16x16x32_f16(af[m], bf[n], acc[m][n], 0, 0, 0);
  }
}

template<int MODE>
__global__ __launch_bounds__(256, 2) void k_gemm(
    const f16* __restrict__ A, const f16* __restrict__ B0,
    const float* __restrict__ aux0, float* __restrict__ out0,
    const float* aux1, const float* aux2, float* out1, f16* out2,
    const f16* __restrict__ zbuf) {
  __shared__ __align__(16) f16 As[128 * 72];
  __shared__ __align__(16) f16 Bs[128 * 72];
  const int tid = threadIdx.x, l = tid & 63, wvi = tid >> 6;
  const int wr = wvi >> 1, wc = wvi & 1;
  const int r0 = blockIdx.y * 128, c0 = blockIdx.x * 128, bz = blockIdx.z;
  constexpr int KS = (MODE == 0) ? 64 : (MODE == 1) ? 24 : (MODE == 2) ? 8 : 32;

  f32x4 acc[4][4];
  f32x4 crun[4][4];
  f32x4 zz = {0.f, 0.f, 0.f, 0.f};
#pragma unroll
  for (int m = 0; m < 4; ++m)
#pragma unroll
    for (int n = 0; n < 4; ++n) { acc[m][n] = zz; crun[m][n] = zz; }

  uint4 av[4], bv[4];
  pref<MODE>(A, B0, zbuf, r0, c0, bz, tid, 0, av, bv);
  for (int s = 0; s < KS; ++s) {
    __syncthreads();
#pragma unroll
    for (int i = 0; i < 4; ++i) {
      int c = i * 256 + tid, row = c >> 3, kc = c & 7;
      *(uint4*)(As + row * 72 + kc * 8) = av[i];
      *(uint4*)(Bs + row * 72 + kc * 8) = bv[i];
    }
    __syncthreads();
    if (s + 1 < KS) pref<MODE>(A, B0, zbuf, r0, c0, bz, tid, s + 1, av, bv);
    mma_step(As, Bs, l, wr, wc, acc);
    if constexpr (MODE == 0) {
      if ((s & 7) == 7) {
        int kb = bz * 8 + (s >> 3);
#pragma unroll
        for (int m = 0; m < 4; ++m) {
          int R = r0 + wr * 64 + m * 16 + ((l >> 4) << 2);
          int rb = (R >= RPB) ? R - RPB : R;
          int f0 = rb >> 1;
          float4 cs = *(const float4*)(aux0 + (size_t)kb * (CPS * 2) + f0 * 2);
#pragma unroll
          for (int n = 0; n < 4; ++n) {
            f32x4 p = acc[m][n];
            crun[m][n].x += cs.x * p.x - cs.y * p.y;
            crun[m][n].y += cs.x * p.y + cs.y * p.x;
            crun[m][n].z += cs.z * p.z - cs.w * p.w;
            crun[m][n].w += cs.z * p.w + cs.w * p.z;
            acc[m][n] = zz;
          }
        }
      }
    }
  }

  if constexpr (MODE == 0) {
    float* P = out0 + (size_t)bz * (512ull * RTOT);
#pragma unroll
    for (int m = 0; m < 4; ++m) {
      int R0 = r0 + wr * 64 + m * 16 + ((l >> 4) << 2);
#pragma unroll
      for (int n = 0; n < 4; ++n) {
        int o = c0 + wc * 64 + n * 16 + (l & 15);
        *(float4*)(P + (size_t)o * RTOT + R0) = *(float4*)&crun[m][n];
      }
    }
  } else if constexpr (MODE == 1) {
#pragma unroll
    for (int m = 0; m < 4; ++m) {
      int o0 = r0 + wr * 64 + m * 16 + ((l >> 4) << 2);
#pragma unroll
      for (int n = 0; n < 4; ++n) {
        int r = c0 + wc * 64 + n * 16 + (l & 15);
        float4 xv = *(const float4*)(aux1 + (size_t)r * 512 + o0);
        float4 sv = *(const float4*)(aux2 + (size_t)r * 512 + o0);
        f32x4 a = acc[m][n];
        float4 res = make_float4(xv.x + sv.x + a.x, xv.y + sv.y + a.y,
                                 xv.z + sv.z + a.z, xv.w + sv.w + a.w);
        *(float4*)(out1 + (size_t)r * 512 + o0) = res;
        union { f16 h[4]; uint2 u; } pk;
        pk.h[0] = (f16)res.x; pk.h[1] = (f16)res.y; pk.h[2] = (f16)res.z; pk.h[3] = (f16)res.w;
        *(uint2*)(out2 + (size_t)r * 512 + o0) = pk.u;
      }
    }
  } else if constexpr (MODE == 2) {
#pragma unroll
    for (int m = 0; m < 4; ++m) {
      int jj0 = r0 + wr * 64 + m * 16 + ((l >> 4) << 2);
      int h2 = jj0 >> 1;
#pragma unroll
      for (int n = 0; n < 4; ++n) {
        int r = c0 + wc * 64 + n * 16 + (l & 15);
        f32x4 a = acc[m][n];
        float v0 = a.x * (a.y / (1.f + __expf(-a.y)));
        float v1 = a.z * (a.w / (1.f + __expf(-a.w)));
        union { f16 h[2]; unsigned u; } pk;
        pk.h[0] = (f16)v0; pk.h[1] = (f16)v1;
        *(unsigned*)(out2 + (size_t)r * 2048 + h2) = pk.u;
      }
    }
  } else {
#pragma unroll
    for (int m = 0; m < 4; ++m) {
      int o0 = r0 + wr * 64 + m * 16 + ((l >> 4) << 2);
#pragma unroll
      for (int n = 0; n < 4; ++n) {
        int r = c0 + wc * 64 + n * 16 + (l & 15);
        float4 xv  = *(const float4*)(aux1 + (size_t)r * 512 + o0);
        float4 x1v = *(const float4*)(aux2 + (size_t)r * 512 + o0);
        f32x4 a = acc[m][n];
        float4 res = make_float4(xv.x + x1v.x + a.x, xv.y + x1v.y + a.y,
                                 xv.z + x1v.z + a.z, xv.w + x1v.w + a.w);
        *(float4*)(out1 + (size_t)r * 512 + o0) = res;
      }
    }
  }
}

// ---------------- small projections ----------------
__global__ void k_inproj(const float* __restrict__ inp, const float* __restrict__ W,
                         float* __restrict__ x) {
  __shared__ float row[64];
  int r = blockIdx.x, tid = threadIdx.x;
  if (tid < 64) row[tid] = inp[(size_t)r * 64 + tid];
  __syncthreads();
  for (int o = tid; o < 512; o += 256) {
    const float* wr = W + (size_t)o * 64;
    float acc = 0.f;
#pragma unroll 8
    for (int q = 0; q < 64; ++q) acc += row[q] * wr[q];
    x[(size_t)r * 512 + o] = acc;
  }
}

__global__ void k_outproj(const float* __restrict__ x, const float* __restrict__ W,
                          float* out, int add) {
  __shared__ float row[512];
  int r = blockIdx.x, tid = threadIdx.x;
  for (int i = tid; i < 512; i += 64) row[i] = x[(size_t)r * 512 + i];
  __syncthreads();
  const float* wr = W + (size_t)tid * 512;
  float acc = 0.f;
  for (int q = 0; q < 512; ++q) acc += row[q] * wr[q];
  if (add) out[(size_t)r * 64 + tid] += acc;
  else     out[(size_t)r * 64 + tid] = acc;
}

// ---------------- host ----------------
extern "C" void kernel_launch(void* const* d_in, const int* in_sizes, int n_in,
                              void* d_out, int out_size, void* d_ws, size_t ws_size,
                              hipStream_t stream) {
  const float* inputs    = (const float*)d_in[0];
  const float* sigma     = (const float*)d_in[1];
  const float* phi       = (const float*)d_in[2];
  const float* in_proj_w = (const float*)d_in[3];
  const float* rn_w      = (const float*)d_in[4];
  const float* M_u       = (const float*)d_in[5];
  const float* M_phi_p   = (const float*)d_in[6];
  const float* M_phi_m   = (const float*)d_in[7];
  const float* fc1       = (const float*)d_in[8];
  const float* fc2       = (const float*)d_in[9];
  const float* out_proj_w= (const float*)d_in[10];
  float* out = (float*)d_out;

  char* ws = (char*)d_ws;
  size_t off = 0;
  auto alloc = [&](size_t bytes) -> void* {
    void* p = ws + off;
    off += (bytes + 255) & ~(size_t)255;
    return p;
  };
  f16*    zbuf = (f16*)alloc(4096);
  float2* tw   = (float2*)alloc(1024 * 8);
  float2* Vf   = (float2*)alloc((size_t)16 * 1025 * 8);
  float2* cpcm = (float2*)alloc((size_t)32 * CPS * 8);
  float*  x    = (float*)alloc((size_t)NROW * 512 * 4);
  float*  h    = (float*)alloc((size_t)NROW * 512 * 4);
  f16*    hb   = (f16*)alloc((size_t)NROW * 512 * 2);
  float*  x1   = (float*)alloc((size_t)NROW * 512 * 4);
  f16*    x1b  = (f16*)alloc((size_t)NROW * 512 * 2);
  float*  spec = (float*)alloc((size_t)NROW * 512 * 4);
  f16*    Xbf  = (f16*)alloc((size_t)RTOT * 512 * 2);
  float*  P    = (float*)alloc((size_t)4 * 512 * RTOT * 4);
  f16*    g1   = (f16*)alloc((size_t)NROW * 2048 * 2);
  f16*    Wsp  = (f16*)alloc((size_t)16384 * 512 * 2);
  f16*    Wu   = (f16*)alloc((size_t)512 * 1536 * 2);
  f16*    Wf1  = (f16*)alloc((size_t)4096 * 512 * 2);
  f16*    Wf2  = (f16*)alloc((size_t)512 * 2048 * 2);
  if (off > ws_size) return;  // workspace too small: fail loudly (output stays poisoned)

  hipMemsetAsync(zbuf, 0, 4096, stream);
  k_twiddle<<<4, 256, 0, stream>>>(tw);
  k_fft_phi<<<8, 256, 0, stream>>>(phi, Vf, tw);
  k_cpcm<<<133, 256, 0, stream>>>(Vf, sigma, cpcm);

  for (int m = 0; m < 2; ++m) {
    k_inproj<<<NROW, 256, 0, stream>>>(inputs, in_proj_w + (size_t)m * 512 * 64, x);
    for (int li = 0; li < 2; ++li) {
      int ml = m * 2 + li;
      k_cast<<<3776, 256, 0, stream>>>(
          M_phi_p + (size_t)ml * 16 * 262144, M_phi_m + (size_t)ml * 16 * 262144,
          M_u + (size_t)ml * 3 * 262144, fc1 + (size_t)ml * 4096 * 512,
          fc2 + (size_t)ml * 512 * 2048, Wsp, Wu, Wf1, Wf2);
      k_rmsnorm<<<512, 256, 0, stream>>>(x, rn_w + (size_t)ml * 512, h, hb);
      k_fft_fwd<<<128, 256, 0, stream>>>(h, Xbf, tw);
      k_gemm<0><<<dim3(4, 33, 4), 256, 0, stream>>>(Xbf, Wsp, (const float*)cpcm, P,
                                                    nullptr, nullptr, nullptr, nullptr, zbuf);
      k_fft_inv<<<128, 256, 0, stream>>>(P, spec, tw);
      k_gemm<1><<<dim3(16, 4, 1), 256, 0, stream>>>(Wu, hb, nullptr, nullptr,
                                                    x, spec, x1, x1b, zbuf);
      k_gemm<2><<<dim3(16, 32, 1), 256, 0, stream>>>(Wf1, x1b, nullptr, nullptr,
                                                     nullptr, nullptr, nullptr, g1, zbuf);
      k_gemm<3><<<dim3(16, 4, 1), 256, 0, stream>>>(Wf2, g1, nullptr, nullptr,
                                                    x, x1, x, nullptr, zbuf);
    }
    k_outproj<<<NROW, 64, 0, stream>>>(x, out_proj_w + (size_t)m * 64 * 512, out, m);
  }
}

// Round 2
// 1225.661 us; speedup vs baseline: 2.5591x; 2.5591x over previous
//
#include <hip/hip_runtime.h>
#include <hip/hip_bf16.h>

typedef _Float16 f16;
typedef _Float16 half8 __attribute__((ext_vector_type(8)));
typedef float f32x4 __attribute__((ext_vector_type(4)));

#define S_LEN 1024
#define DMODEL 512
#define NFFT   2048
#define FPAD   1056     // padded f-slots per batch (1025 valid)
#define RPB    2112     // rows per batch = 2*FPAD (re/im interleaved)
#define RTOT   4224     // 2 batches
#define CPS    1064     // cpcm f-stride (padded, zeros past 1024)
#define NROW   2048     // B*S
#define NPART  8        // split-K partials for spectral GEMM

__device__ __forceinline__ float2 mkf2(float a, float b) { float2 r; r.x = a; r.y = b; return r; }

// async global->LDS (16B per lane). LDS dest must be wave-uniform base; lane writes at +lane*16.
__device__ __forceinline__ void gl16(const f16* g, f16* l) {
  __builtin_amdgcn_global_load_lds((const __attribute__((address_space(1))) void*)g,
                                   (__attribute__((address_space(3))) void*)l, 16, 0, 0);
}

// ---------------- FFT-2048 in LDS (radix-2 DIT, bit-reversed input) ----------------
template<bool INV>
__device__ __forceinline__ void fft2048(float2* z, const float2* __restrict__ tw, int tid) {
  for (int i = tid; i < 2048; i += 256) {
    int j = (int)(__brev((unsigned)i) >> 21);
    if (i < j) { float2 a = z[i]; z[i] = z[j]; z[j] = a; }
  }
  __syncthreads();
  for (int sl = 1; sl <= 11; ++sl) {
    int hlf = 1 << (sl - 1);
    for (int idx = tid; idx < 1024; idx += 256) {
      int j = idx & (hlf - 1);
      int base = (idx >> (sl - 1)) << sl;
      float2 wv = tw[j << (11 - sl)];
      if (INV) wv.y = -wv.y;
      float2 a = z[base + j];
      float2 b = z[base + j + hlf];
      float tr = b.x * wv.x - b.y * wv.y;
      float ti = b.x * wv.y + b.y * wv.x;
      z[base + j]       = mkf2(a.x + tr, a.y + ti);
      z[base + j + hlf] = mkf2(a.x - tr, a.y - ti);
    }
    __syncthreads();
  }
}

// ---------------- init kernels ----------------
__global__ void k_twiddle(float2* tw) {
  int i = blockIdx.x * 256 + threadIdx.x;
  if (i < 1024) {
    float ang = -6.2831853071795864769f * (float)i / 2048.0f;
    tw[i] = mkf2(cosf(ang), sinf(ang));   // exp(-2*pi*i*m/2048)
  }
}

// rfft of phi columns (pairs packed into one complex FFT)
__global__ void k_fft_phi(const float* __restrict__ phi, float2* __restrict__ Vf,
                          const float2* __restrict__ tw) {
  __shared__ float2 z[2048];
  int tid = threadIdx.x;
  int k0 = blockIdx.x * 2;
  for (int t = tid; t < 1024; t += 256) {
    float2 v = *(const float2*)(phi + (size_t)t * 16 + k0);
    z[t] = v;
  }
  for (int t = 1024 + tid; t < 2048; t += 256) z[t] = mkf2(0.f, 0.f);
  __syncthreads();
  fft2048<false>(z, tw, tid);
  for (int f = tid; f <= 1024; f += 256) {
    float2 zf = z[f], zc = z[(2048 - f) & 2047];
    Vf[(size_t)k0 * 1025 + f]       = mkf2(0.5f * (zf.x + zc.x), 0.5f * (zf.y - zc.y));
    Vf[(size_t)(k0 + 1) * 1025 + f] = mkf2(0.5f * (zf.y + zc.y), 0.5f * (zc.x - zf.x));
  }
}

// cpcm[kb][f] = sig4[k] * Vf_eff / 2048 ; kb<16: plus (Vf), kb>=16: minus (freq-shifted Vf)
__global__ void k_cpcm(const float2* __restrict__ Vf, const float* __restrict__ sigma,
                       float2* __restrict__ cpcm) {
  int idx = blockIdx.x * 256 + threadIdx.x;
  if (idx >= 32 * CPS) return;
  int kb = idx / CPS, f = idx - kb * CPS;
  float2 v = mkf2(0.f, 0.f);
  if (f <= 1024) {
    int k = kb & 15;
    if (kb < 16) {
      v = Vf[(size_t)k * 1025 + f];
    } else {
      if (f == 0)         v = Vf[(size_t)k * 1025 + 1024];
      else if (f == 1024) v = Vf[(size_t)k * 1025];
      else { float2 t = Vf[(size_t)k * 1025 + (1024 - f)]; v = mkf2(t.x, -t.y); }
    }
    float s = powf(sigma[k], 0.25f) * (1.0f / 2048.0f);
    v.x *= s; v.y *= s;
  }
  cpcm[idx] = v;
}

// ---------------- per-layer weight cast/transpose ----------------
__global__ void k_cast(const float* __restrict__ mp, const float* __restrict__ mm,
                       const float* __restrict__ mu, const float* __restrict__ fc1,
                       const float* __restrict__ fc2,
                       f16* __restrict__ Wsp, f16* __restrict__ Wu,
                       f16* __restrict__ Wf1, f16* __restrict__ Wf2) {
  __shared__ float T[64][65];
  int blk = blockIdx.x, tid = threadIdx.x;
  if (blk < 2048) {                    // Wsp: Wsp[(kb*512+o)][d] = m?[k][d][o]
    int mat = blk >> 6, tile = blk & 63;
    int d0 = (tile >> 3) * 64, o0 = (tile & 7) * 64;
    const float* src = (mat < 16) ? (mp + (size_t)mat * 262144)
                                  : (mm + (size_t)(mat - 16) * 262144);
    for (int q = tid; q < 4096; q += 256) {
      int i = q >> 6, j = q & 63;
      T[i][j] = src[(size_t)(d0 + i) * 512 + o0 + j];
    }
    __syncthreads();
    for (int q = tid; q < 4096; q += 256) {
      int i = q >> 6, j = q & 63;
      Wsp[(size_t)(mat * 512 + o0 + i) * 512 + d0 + j] = (f16)T[j][i];
    }
  } else if (blk < 2240) {             // Wu: Wu[o][ip*512+d] = mu[2-ip][d][o]
    int q0 = blk - 2048;
    int ip = q0 >> 6, tile = q0 & 63;
    int d0 = (tile >> 3) * 64, o0 = (tile & 7) * 64;
    const float* src = mu + (size_t)(2 - ip) * 262144;
    for (int q = tid; q < 4096; q += 256) {
      int i = q >> 6, j = q & 63;
      T[i][j] = src[(size_t)(d0 + i) * 512 + o0 + j];
    }
    __syncthreads();
    for (int q = tid; q < 4096; q += 256) {
      int i = q >> 6, j = q & 63;
      Wu[(size_t)(o0 + i) * 1536 + ip * 512 + d0 + j] = (f16)T[j][i];
    }
  } else if (blk < 3264) {             // fc1 perm copy: row 2h = y-row h, 2h+1 = gate-row h
    int q0 = blk - 2240;
    size_t e = ((size_t)q0 * 256 + tid) * 8;
    int jj = (int)(e >> 9), col = (int)(e & 511);
    int srow = (jj & 1) ? (2048 + (jj >> 1)) : (jj >> 1);
    const float4* s = (const float4*)(fc1 + (size_t)srow * 512 + col);
    float4 a = s[0], b = s[1];
    union { f16 h[8]; uint4 u; } pk;
    pk.h[0] = (f16)a.x; pk.h[1] = (f16)a.y; pk.h[2] = (f16)a.z; pk.h[3] = (f16)a.w;
    pk.h[4] = (f16)b.x; pk.h[5] = (f16)b.y; pk.h[6] = (f16)b.z; pk.h[7] = (f16)b.w;
    *(uint4*)(Wf1 + (size_t)jj * 512 + col) = pk.u;
  } else {                             // fc2 straight copy (already [o][j])
    int q0 = blk - 3264;
    size_t e = ((size_t)q0 * 256 + tid) * 8;
    const float4* s = (const float4*)(fc2 + e);
    float4 a = s[0], b = s[1];
    union { f16 h[8]; uint4 u; } pk;
    pk.h[0] = (f16)a.x; pk.h[1] = (f16)a.y; pk.h[2] = (f16)a.z; pk.h[3] = (f16)a.w;
    pk.h[4] = (f16)b.x; pk.h[5] = (f16)b.y; pk.h[6] = (f16)b.z; pk.h[7] = (f16)b.w;
    *(uint4*)(Wf2 + e) = pk.u;
  }
}

// ---------------- rmsnorm (writes f32 h and zero-padded fp16 hb2) ----------------
__global__ void k_rmsnorm(const float* __restrict__ x, const float* __restrict__ w,
                          float* __restrict__ h, f16* __restrict__ hb2) {
  int tid = threadIdx.x, l = tid & 63, wv = tid >> 6;
  int r = blockIdx.x * 4 + wv;
  int b = r >> 10, t = r & 1023;
  const float* xr = x + (size_t)r * 512;
  f16* hr = hb2 + (size_t)(b * 1026 + 2 + t) * 512;
  float v[8]; float ss = 0.f;
#pragma unroll
  for (int j = 0; j < 8; ++j) { v[j] = xr[j * 64 + l]; ss += v[j] * v[j]; }
#pragma unroll
  for (int o = 32; o; o >>= 1) ss += __shfl_xor(ss, o, 64);
  float rn = rsqrtf(ss * (1.f / 512.f) + 1e-5f);
#pragma unroll
  for (int j = 0; j < 8; ++j) {
    float hv = v[j] * rn * w[j * 64 + l];
    h[(size_t)r * 512 + j * 64 + l] = hv;
    hr[j * 64 + l] = (f16)hv;
  }
}

// ---------------- forward FFT of h -> Xbf (fp16, rows (b, f, re/im)) ----------------
__global__ void k_fft_fwd(const float* __restrict__ h, f16* __restrict__ Xbf,
                          const float2* __restrict__ tw) {
  __shared__ float2 z[2048];
  __shared__ __align__(16) f16 Xst[RPB * 8];
  int tid = threadIdx.x;
  int b = blockIdx.x >> 6;
  int dg = (blockIdx.x & 63) * 8;
  for (int i = tid; i < 62 * 8; i += 256) Xst[(2050 + (i >> 3)) * 8 + (i & 7)] = (f16)0.f;
  for (int c4 = 0; c4 < 4; ++c4) {
    int d0 = dg + 2 * c4;
    __syncthreads();
    for (int t = tid; t < 1024; t += 256)
      z[t] = *(const float2*)(h + (size_t)(b * 1024 + t) * 512 + d0);
    for (int t = 1024 + tid; t < 2048; t += 256) z[t] = mkf2(0.f, 0.f);
    __syncthreads();
    fft2048<false>(z, tw, tid);
    for (int f = tid; f <= 1024; f += 256) {
      float2 zf = z[f], zc = z[(2048 - f) & 2047];
      float x0r = 0.5f * (zf.x + zc.x), x0i = 0.5f * (zf.y - zc.y);
      float x1r = 0.5f * (zf.y + zc.y), x1i = 0.5f * (zc.x - zf.x);
      Xst[(2 * f) * 8 + 2 * c4]         = (f16)x0r;
      Xst[(2 * f + 1) * 8 + 2 * c4]     = (f16)x0i;
      Xst[(2 * f) * 8 + 2 * c4 + 1]     = (f16)x1r;
      Xst[(2 * f + 1) * 8 + 2 * c4 + 1] = (f16)x1i;
    }
  }
  __syncthreads();
  for (int i = tid; i < RPB; i += 256)
    *(uint4*)(Xbf + (size_t)(b * RPB + i) * 512 + dg) = *(const uint4*)&Xst[i * 8];
}

// ---------------- inverse FFT: sum of NPART f16 partials -> spec ----------------
__global__ void k_fft_inv(const f16* __restrict__ P, float* __restrict__ spec,
                          const float2* __restrict__ tw) {
  __shared__ float2 z[2048];
  __shared__ __align__(16) float Sst[1024 * 8];
  int tid = threadIdx.x;
  int b = blockIdx.x >> 6;
  int og = (blockIdx.x & 63) * 8;
  for (int c4 = 0; c4 < 4; ++c4) {
    int o0 = og + 2 * c4;
    __syncthreads();
    for (int f = tid; f <= 1024; f += 256) {
      size_t base0 = (size_t)o0 * RTOT + (size_t)b * RPB + 2 * f;
      float s0r = 0.f, s0i = 0.f, s1r = 0.f, s1i = 0.f;
#pragma unroll
      for (int g = 0; g < NPART; ++g) {
        const f16* Pg = P + (size_t)g * 512 * RTOT;
        union { unsigned u; f16 h[2]; } ua, uc;
        ua.u = *(const unsigned*)(Pg + base0);
        uc.u = *(const unsigned*)(Pg + base0 + RTOT);
        s0r += (float)ua.h[0]; s0i += (float)ua.h[1];
        s1r += (float)uc.h[0]; s1i += (float)uc.h[1];
      }
      z[f] = mkf2(s0r - s1i, s0i + s1r);
      if (f >= 1 && f <= 1023) z[2048 - f] = mkf2(s0r + s1i, s1r - s0i);
    }
    __syncthreads();
    fft2048<true>(z, tw, tid);
    for (int t = tid; t < 1024; t += 256) {
      Sst[t * 8 + 2 * c4]     = z[t].x;
      Sst[t * 8 + 2 * c4 + 1] = z[t].y;
    }
  }
  __syncthreads();
  for (int i = tid; i < 1024; i += 256) {
    float* dst = spec + (size_t)(b * 1024 + i) * 512 + og;
    *(float4*)dst       = *(const float4*)&Sst[i * 8];
    *(float4*)(dst + 4) = *(const float4*)&Sst[i * 8 + 4];
  }
}

// ---------------- unified MFMA GEMM (BM=MR*32 x BN=NR*32 tile, BK=64, 4 waves) ----------------
// Staging: global_load_lds 16B/lane, LDS linear [rows][64] f16, XOR swizzle (chunk ^= row&7)
// applied on the per-lane GLOBAL source address (write side) and on ds_read address (read side).
// MODE 0: spectral  C-rows=(b,f,c) A=Xbf   C-cols=o  B=Wsp (kb loop, complex-scale) -> P[bz] f16
// MODE 1: AR        C-rows=o       A=Wu    C-cols=r  B=hb2 (padded window)  -> x1 = x+spec+acc
// MODE 2: MLP1      C-rows=jj      A=fc1p  C-cols=r  B=x1b                  -> g1 = y*silu(gate)
// MODE 3: MLP2      C-rows=o       A=fc2   C-cols=r  B=g1                   -> x = x + x1 + acc
template<int MODE, int MR, int NR>
__device__ __forceinline__ void stage(const f16* __restrict__ A, const f16* __restrict__ B0,
                                      int r0, int c0, int bz, int tid, int s,
                                      f16* As, f16* Bs) {
  constexpr int LDA = (MODE == 0) ? 512 : (MODE == 1) ? 1536 : (MODE == 2) ? 512 : 2048;
  const int kA = (MODE == 0) ? ((s & 7) * 64) : s * 64;
  const int rowl = tid >> 3;
  const int lc8 = ((tid & 7) ^ (rowl & 7)) * 8;   // logical chunk * 8 (f16)
  f16* lA = As + ((tid >> 6) << 9);               // wave-uniform LDS base
  f16* lB = Bs + ((tid >> 6) << 9);
#pragma unroll
  for (int i = 0; i < MR; ++i) {
    int row = i * 32 + rowl;
    gl16(A + (size_t)(r0 + row) * LDA + kA + lc8, lA + i * 2048);
  }
#pragma unroll
  for (int i = 0; i < NR; ++i) {
    int row = i * 32 + rowl;
    const f16* bs;
    if constexpr (MODE == 0) {
      int kb = bz * 4 + (s >> 3);
      bs = B0 + (size_t)(kb * 512 + c0 + row) * 512 + (s & 7) * 64 + lc8;
    } else if constexpr (MODE == 1) {
      int ip = s >> 3, d0 = (s & 7) * 64;
      int rr = c0 + row;
      int b = rr >> 10, t = rr & 1023;
      bs = B0 + (size_t)(b * 1026 + t + ip) * 512 + d0 + lc8;   // pad rows are zero
    } else {
      constexpr int LDB = (MODE == 2) ? 512 : 2048;
      bs = B0 + (size_t)(c0 + row) * LDB + s * 64 + lc8;
    }
    gl16(bs, lB + i * 2048);
  }
}

template<int MR, int NR>
__device__ __forceinline__ void mma_step(const f16* As, const f16* Bs, int l, int wr, int wc,
                                         f32x4 acc[MR][NR]) {
  const int lr = l & 15, kg = l >> 4, sw = l & 7;
#pragma unroll
  for (int kk = 0; kk < 2; ++kk) {
    half8 af[MR], bf[NR];
    const int pc8 = (((kk * 4 + kg) ^ sw) << 3);
#pragma unroll
    for (int m = 0; m < MR; ++m)
      af[m] = *(const half8*)(As + (wr * (MR * 16) + m * 16 + lr) * 64 + pc8);
#pragma unroll
    for (int n = 0; n < NR; ++n)
      bf[n] = *(const half8*)(Bs + (wc * (NR * 16) + n * 16 + lr) * 64 + pc8);
#pragma unroll
    for (int m = 0; m < MR; ++m)
#pragma unroll
      for (int n = 0; n < NR; ++n)
        acc[m][n] = __builtin_amdgcn_mfma_f32_16x16x32_f16(af[m], bf[n], acc[m][n], 0, 0, 0);
  }
}

template<int MODE, int MR, int NR>
__global__ __launch_bounds__(256, (MODE == 0) ? 2 : ((MODE == 2) ? 3 : 4))
void k_gemm(const f16* __restrict__ A, const f16* __restrict__ B0,
            const float* __restrict__ aux0, const float* aux1, const float* aux2,
            float* out1, f16* __restrict__ out2) {
  __shared__ __align__(16) f16 As[MR * 32 * 64];
  __shared__ __align__(16) f16 Bs[NR * 32 * 64];
  const int tid = threadIdx.x, l = tid & 63, wvi = tid >> 6;
  const int wr = wvi >> 1, wc = wvi & 1;
  int bx, by, bz;
  if constexpr (MODE == 0) {           // 1D grid of 1056, XCD chunk swizzle (1056 = 8*132)
    int wg = (int)blockIdx.x;
    wg = (wg & 7) * 132 + (wg >> 3);
    bz = wg / 132; int rem = wg - bz * 132;
    by = rem >> 2; bx = rem & 3;
  } else { bx = blockIdx.x; by = blockIdx.y; bz = 0; }
  const int r0 = by * (MR * 32), c0 = bx * (NR * 32);
  constexpr int KS = (MODE == 0) ? 32 : (MODE == 1) ? 24 : (MODE == 2) ? 8 : 32;

  f32x4 acc[MR][NR];
  f32x4 crun[MR][NR];
  f32x4 zz = {0.f, 0.f, 0.f, 0.f};
#pragma unroll
  for (int m = 0; m < MR; ++m)
#pragma unroll
    for (int n = 0; n < NR; ++n) { acc[m][n] = zz; crun[m][n] = zz; }

  for (int s = 0; s < KS; ++s) {
    __syncthreads();                               // previous compute done
    stage<MODE, MR, NR>(A, B0, r0, c0, bz, tid, s, As, Bs);
    __syncthreads();                               // vmcnt(0) drain: staging landed
    mma_step<MR, NR>(As, Bs, l, wr, wc, acc);
    if constexpr (MODE == 0) {
      if ((s & 7) == 7) {
        int kb = bz * 4 + (s >> 3);
#pragma unroll
        for (int m = 0; m < MR; ++m) {
          int R = r0 + wr * (MR * 16) + m * 16 + ((l >> 4) << 2);
          int rb = (R >= RPB) ? R - RPB : R;
          int f0 = rb >> 1;
          float4 cs = *(const float4*)(aux0 + (size_t)kb * (CPS * 2) + f0 * 2);
#pragma unroll
          for (int n = 0; n < NR; ++n) {
            f32x4 p = acc[m][n];
            crun[m][n].x += cs.x * p.x - cs.y * p.y;
            crun[m][n].y += cs.x * p.y + cs.y * p.x;
            crun[m][n].z += cs.z * p.z - cs.w * p.w;
            crun[m][n].w += cs.z * p.w + cs.w * p.z;
            acc[m][n] = zz;
          }
        }
      }
    }
  }

  if constexpr (MODE == 0) {
    f16* P = out2 + (size_t)bz * (512ull * RTOT);
#pragma unroll
    for (int m = 0; m < MR; ++m) {
      int R0 = r0 + wr * (MR * 16) + m * 16 + ((l >> 4) << 2);
#pragma unroll
      for (int n = 0; n < NR; ++n) {
        int o = c0 + wc * (NR * 16) + n * 16 + (l & 15);
        union { f16 h[4]; uint2 u; } pk;
        pk.h[0] = (f16)crun[m][n].x; pk.h[1] = (f16)crun[m][n].y;
        pk.h[2] = (f16)crun[m][n].z; pk.h[3] = (f16)crun[m][n].w;
        *(uint2*)(P + (size_t)o * RTOT + R0) = pk.u;
      }
    }
  } else if constexpr (MODE == 1) {
#pragma unroll
    for (int m = 0; m < MR; ++m) {
      int o0 = r0 + wr * (MR * 16) + m * 16 + ((l >> 4) << 2);
#pragma unroll
      for (int n = 0; n < NR; ++n) {
        int r = c0 + wc * (NR * 16) + n * 16 + (l & 15);
        float4 xv = *(const float4*)(aux1 + (size_t)r * 512 + o0);
        float4 sv = *(const float4*)(aux2 + (size_t)r * 512 + o0);
        f32x4 a = acc[m][n];
        float4 res = make_float4(xv.x + sv.x + a.x, xv.y + sv.y + a.y,
                                 xv.z + sv.z + a.z, xv.w + sv.w + a.w);
        *(float4*)(out1 + (size_t)r * 512 + o0) = res;
        union { f16 h[4]; uint2 u; } pk;
        pk.h[0] = (f16)res.x; pk.h[1] = (f16)res.y; pk.h[2] = (f16)res.z; pk.h[3] = (f16)res.w;
        *(uint2*)(out2 + (size_t)r * 512 + o0) = pk.u;
      }
    }
  } else if constexpr (MODE == 2) {
#pragma unroll
    for (int m = 0; m < MR; ++m) {
      int jj0 = r0 + wr * (MR * 16) + m * 16 + ((l >> 4) << 2);
      int h2 = jj0 >> 1;
#pragma unroll
      for (int n = 0; n < NR; ++n) {
        int r = c0 + wc * (NR * 16) + n * 16 + (l & 15);
        f32x4 a = acc[m][n];
        float v0 = a.x * (a.y / (1.f + __expf(-a.y)));
        float v1 = a.z * (a.w / (1.f + __expf(-a.w)));
        union { f16 h[2]; unsigned u; } pk;
        pk.h[0] = (f16)v0; pk.h[1] = (f16)v1;
        *(unsigned*)(out2 + (size_t)r * 2048 + h2) = pk.u;
      }
    }
  } else {
#pragma unroll
    for (int m = 0; m < MR; ++m) {
      int o0 = r0 + wr * (MR * 16) + m * 16 + ((l >> 4) << 2);
#pragma unroll
      for (int n = 0; n < NR; ++n) {
        int r = c0 + wc * (NR * 16) + n * 16 + (l & 15);
        float4 xv  = *(const float4*)(aux1 + (size_t)r * 512 + o0);
        float4 x1v = *(const float4*)(aux2 + (size_t)r * 512 + o0);
        f32x4 a = acc[m][n];
        float4 res = make_float4(xv.x + x1v.x + a.x, xv.y + x1v.y + a.y,
                                 xv.z + x1v.z + a.z, xv.w + x1v.w + a.w);
        *(float4*)(out1 + (size_t)r * 512 + o0) = res;
      }
    }
  }
}

// ---------------- small projections ----------------
__global__ void k_inproj(const float* __restrict__ inp, const float* __restrict__ W,
                         float* __restrict__ x) {
  __shared__ float row[64];
  int r = blockIdx.x, tid = threadIdx.x;
  if (tid < 64) row[tid] = inp[(size_t)r * 64 + tid];
  __syncthreads();
  for (int o = tid; o < 512; o += 256) {
    const float* wr = W + (size_t)o * 64;
    float acc = 0.f;
#pragma unroll 8
    for (int q = 0; q < 64; ++q) acc += row[q] * wr[q];
    x[(size_t)r * 512 + o] = acc;
  }
}

__global__ void k_outproj(const float* __restrict__ x, const float* __restrict__ W,
                          float* out, int add) {
  __shared__ float row[512];
  int r = blockIdx.x, tid = threadIdx.x;
  for (int i = tid; i < 512; i += 64) row[i] = x[(size_t)r * 512 + i];
  __syncthreads();
  const float* wr = W + (size_t)tid * 512;
  float acc = 0.f;
  for (int q = 0; q < 512; ++q) acc += row[q] * wr[q];
  if (add) out[(size_t)r * 64 + tid] += acc;
  else     out[(size_t)r * 64 + tid] = acc;
}

// ---------------- host ----------------
extern "C" void kernel_launch(void* const* d_in, const int* in_sizes, int n_in,
                              void* d_out, int out_size, void* d_ws, size_t ws_size,
                              hipStream_t stream) {
  const float* inputs    = (const float*)d_in[0];
  const float* sigma     = (const float*)d_in[1];
  const float* phi       = (const float*)d_in[2];
  const float* in_proj_w = (const float*)d_in[3];
  const float* rn_w      = (const float*)d_in[4];
  const float* M_u       = (const float*)d_in[5];
  const float* M_phi_p   = (const float*)d_in[6];
  const float* M_phi_m   = (const float*)d_in[7];
  const float* fc1       = (const float*)d_in[8];
  const float* fc2       = (const float*)d_in[9];
  const float* out_proj_w= (const float*)d_in[10];
  float* out = (float*)d_out;

  char* ws = (char*)d_ws;
  size_t off = 0;
  auto alloc = [&](size_t bytes) -> void* {
    void* p = ws + off;
    off += (bytes + 255) & ~(size_t)255;
    return p;
  };
  float2* tw   = (float2*)alloc(1024 * 8);
  float2* Vf   = (float2*)alloc((size_t)16 * 1025 * 8);
  float2* cpcm = (float2*)alloc((size_t)32 * CPS * 8);
  float*  x    = (float*)alloc((size_t)NROW * 512 * 4);
  float*  h    = (float*)alloc((size_t)NROW * 512 * 4);
  f16*    hb2  = (f16*)alloc((size_t)2052 * 512 * 2);   // 2 batches x (2 pad + 1024) rows
  float*  x1   = (float*)alloc((size_t)NROW * 512 * 4);
  f16*    x1b  = (f16*)alloc((size_t)NROW * 512 * 2);
  float*  spec = (float*)alloc((size_t)NROW * 512 * 4);
  f16*    Xbf  = (f16*)alloc((size_t)RTOT * 512 * 2);
  f16*    P    = (f16*)alloc((size_t)NPART * 512 * RTOT * 2);
  f16*    g1   = (f16*)alloc((size_t)NROW * 2048 * 2);
  f16*    Wsp  = (f16*)alloc((size_t)16384 * 512 * 2);
  f16*    Wu   = (f16*)alloc((size_t)512 * 1536 * 2);
  f16*    Wf1  = (f16*)alloc((size_t)4096 * 512 * 2);
  f16*    Wf2  = (f16*)alloc((size_t)512 * 2048 * 2);
  if (off > ws_size) return;  // workspace too small: fail loudly (output stays poisoned)

  // zero the AR window pad rows (rows 0,1 of each batch block in hb2)
  hipMemsetAsync(hb2, 0, 2 * 512 * sizeof(f16), stream);
  hipMemsetAsync(hb2 + (size_t)1026 * 512, 0, 2 * 512 * sizeof(f16), stream);
  k_twiddle<<<4, 256, 0, stream>>>(tw);
  k_fft_phi<<<8, 256, 0, stream>>>(phi, Vf, tw);
  k_cpcm<<<133, 256, 0, stream>>>(Vf, sigma, cpcm);

  for (int m = 0; m < 2; ++m) {
    k_inproj<<<NROW, 256, 0, stream>>>(inputs, in_proj_w + (size_t)m * 512 * 64, x);
    for (int li = 0; li < 2; ++li) {
      int ml = m * 2 + li;
      k_cast<<<3776, 256, 0, stream>>>(
          M_phi_p + (size_t)ml * 16 * 262144, M_phi_m + (size_t)ml * 16 * 262144,
          M_u + (size_t)ml * 3 * 262144, fc1 + (size_t)ml * 4096 * 512,
          fc2 + (size_t)ml * 512 * 2048, Wsp, Wu, Wf1, Wf2);
      k_rmsnorm<<<512, 256, 0, stream>>>(x, rn_w + (size_t)ml * 512, h, hb2);
      k_fft_fwd<<<128, 256, 0, stream>>>(h, Xbf, tw);
      k_gemm<0, 4, 4><<<dim3(1056), 256, 0, stream>>>(Xbf, Wsp, (const float*)cpcm,
                                                      nullptr, nullptr, nullptr, P);
      k_fft_inv<<<128, 256, 0, stream>>>(P, spec, tw);
      k_gemm<1, 2, 4><<<dim3(16, 8), 256, 0, stream>>>(Wu, hb2, nullptr,
                                                       x, spec, x1, x1b);
      k_gemm<2, 4, 4><<<dim3(16, 32), 256, 0, stream>>>(Wf1, x1b, nullptr,
                                                        nullptr, nullptr, nullptr, g1);
      k_gemm<3, 2, 4><<<dim3(16, 8), 256, 0, stream>>>(Wf2, g1, nullptr,
                                                       x, x1, x, nullptr);
    }
    k_outproj<<<NROW, 64, 0, stream>>>(x, out_proj_w + (size_t)m * 64 * 512, out, m);
  }
}

// Round 3
// 1108.242 us; speedup vs baseline: 2.8303x; 1.1060x over previous
//
#include <hip/hip_runtime.h>
#include <hip/hip_bf16.h>

typedef _Float16 f16;
typedef _Float16 half8 __attribute__((ext_vector_type(8)));
typedef float f32x4 __attribute__((ext_vector_type(4)));

#define S_LEN 1024
#define DMODEL 512
#define NFFT   2048
#define FPAD   1056     // padded f-slots per batch (1025 valid)
#define RPB    2112     // rows per batch = 2*FPAD (re/im interleaved)
#define RTOT   4224     // 2 batches
#define CPS    1064     // cpcm f-stride (padded, zeros past 1024)
#define NROW   2048     // B*S
#define NPART  8        // split-K partials for spectral GEMM

__device__ __forceinline__ float2 mkf2(float a, float b) { float2 r; r.x = a; r.y = b; return r; }

// async global->LDS (16B per lane). LDS dest must be wave-uniform base; lane writes at +lane*16.
__device__ __forceinline__ void gl16(const f16* g, f16* l) {
  __builtin_amdgcn_global_load_lds((const __attribute__((address_space(1))) void*)g,
                                   (__attribute__((address_space(3))) void*)l, 16, 0, 0);
}

template<int N> __device__ __forceinline__ void wait_vmcnt() {
  if constexpr (N == 8)      asm volatile("s_waitcnt vmcnt(8)" ::: "memory");
  else if constexpr (N == 4) asm volatile("s_waitcnt vmcnt(4)" ::: "memory");
  else                       asm volatile("s_waitcnt vmcnt(0)" ::: "memory");
}

// ---------------- FFT-2048 in LDS (radix-2 DIT, bit-reversed input) ----------------
template<bool INV>
__device__ __forceinline__ void fft2048(float2* z, const float2* __restrict__ tw, int tid) {
  for (int i = tid; i < 2048; i += 256) {
    int j = (int)(__brev((unsigned)i) >> 21);
    if (i < j) { float2 a = z[i]; z[i] = z[j]; z[j] = a; }
  }
  __syncthreads();
  for (int sl = 1; sl <= 11; ++sl) {
    int hlf = 1 << (sl - 1);
    for (int idx = tid; idx < 1024; idx += 256) {
      int j = idx & (hlf - 1);
      int base = (idx >> (sl - 1)) << sl;
      float2 wv = tw[j << (11 - sl)];
      if (INV) wv.y = -wv.y;
      float2 a = z[base + j];
      float2 b = z[base + j + hlf];
      float tr = b.x * wv.x - b.y * wv.y;
      float ti = b.x * wv.y + b.y * wv.x;
      z[base + j]       = mkf2(a.x + tr, a.y + ti);
      z[base + j + hlf] = mkf2(a.x - tr, a.y - ti);
    }
    __syncthreads();
  }
}

// ---------------- init kernels ----------------
__global__ void k_twiddle(float2* tw) {
  int i = blockIdx.x * 256 + threadIdx.x;
  if (i < 1024) {
    float ang = -6.2831853071795864769f * (float)i / 2048.0f;
    tw[i] = mkf2(cosf(ang), sinf(ang));   // exp(-2*pi*i*m/2048)
  }
}

// rfft of phi columns (pairs packed into one complex FFT)
__global__ void k_fft_phi(const float* __restrict__ phi, float2* __restrict__ Vf,
                          const float2* __restrict__ tw) {
  __shared__ float2 z[2048];
  int tid = threadIdx.x;
  int k0 = blockIdx.x * 2;
  for (int t = tid; t < 1024; t += 256) {
    float2 v = *(const float2*)(phi + (size_t)t * 16 + k0);
    z[t] = v;
  }
  for (int t = 1024 + tid; t < 2048; t += 256) z[t] = mkf2(0.f, 0.f);
  __syncthreads();
  fft2048<false>(z, tw, tid);
  for (int f = tid; f <= 1024; f += 256) {
    float2 zf = z[f], zc = z[(2048 - f) & 2047];
    Vf[(size_t)k0 * 1025 + f]       = mkf2(0.5f * (zf.x + zc.x), 0.5f * (zf.y - zc.y));
    Vf[(size_t)(k0 + 1) * 1025 + f] = mkf2(0.5f * (zf.y + zc.y), 0.5f * (zc.x - zf.x));
  }
}

// cpcm[kb][f] = sig4[k] * Vf_eff / 2048 ; kb<16: plus (Vf), kb>=16: minus (freq-shifted Vf)
__global__ void k_cpcm(const float2* __restrict__ Vf, const float* __restrict__ sigma,
                       float2* __restrict__ cpcm) {
  int idx = blockIdx.x * 256 + threadIdx.x;
  if (idx >= 32 * CPS) return;
  int kb = idx / CPS, f = idx - kb * CPS;
  float2 v = mkf2(0.f, 0.f);
  if (f <= 1024) {
    int k = kb & 15;
    if (kb < 16) {
      v = Vf[(size_t)k * 1025 + f];
    } else {
      if (f == 0)         v = Vf[(size_t)k * 1025 + 1024];
      else if (f == 1024) v = Vf[(size_t)k * 1025];
      else { float2 t = Vf[(size_t)k * 1025 + (1024 - f)]; v = mkf2(t.x, -t.y); }
    }
    float s = powf(sigma[k], 0.25f) * (1.0f / 2048.0f);
    v.x *= s; v.y *= s;
  }
  cpcm[idx] = v;
}

// ---------------- per-layer weight cast/transpose ----------------
__global__ void k_cast(const float* __restrict__ mp, const float* __restrict__ mm,
                       const float* __restrict__ mu, const float* __restrict__ fc1,
                       const float* __restrict__ fc2,
                       f16* __restrict__ Wsp, f16* __restrict__ Wu,
                       f16* __restrict__ Wf1, f16* __restrict__ Wf2) {
  __shared__ float T[64][65];
  int blk = blockIdx.x, tid = threadIdx.x;
  if (blk < 2048) {                    // Wsp: Wsp[(kb*512+o)][d] = m?[k][d][o]
    int mat = blk >> 6, tile = blk & 63;
    int d0 = (tile >> 3) * 64, o0 = (tile & 7) * 64;
    const float* src = (mat < 16) ? (mp + (size_t)mat * 262144)
                                  : (mm + (size_t)(mat - 16) * 262144);
    for (int q = tid; q < 4096; q += 256) {
      int i = q >> 6, j = q & 63;
      T[i][j] = src[(size_t)(d0 + i) * 512 + o0 + j];
    }
    __syncthreads();
    for (int q = tid; q < 4096; q += 256) {
      int i = q >> 6, j = q & 63;
      Wsp[(size_t)(mat * 512 + o0 + i) * 512 + d0 + j] = (f16)T[j][i];
    }
  } else if (blk < 2240) {             // Wu: Wu[o][ip*512+d] = mu[2-ip][d][o]
    int q0 = blk - 2048;
    int ip = q0 >> 6, tile = q0 & 63;
    int d0 = (tile >> 3) * 64, o0 = (tile & 7) * 64;
    const float* src = mu + (size_t)(2 - ip) * 262144;
    for (int q = tid; q < 4096; q += 256) {
      int i = q >> 6, j = q & 63;
      T[i][j] = src[(size_t)(d0 + i) * 512 + o0 + j];
    }
    __syncthreads();
    for (int q = tid; q < 4096; q += 256) {
      int i = q >> 6, j = q & 63;
      Wu[(size_t)(o0 + i) * 1536 + ip * 512 + d0 + j] = (f16)T[j][i];
    }
  } else if (blk < 3264) {             // fc1 perm copy: row 2h = y-row h, 2h+1 = gate-row h
    int q0 = blk - 2240;
    size_t e = ((size_t)q0 * 256 + tid) * 8;
    int jj = (int)(e >> 9), col = (int)(e & 511);
    int srow = (jj & 1) ? (2048 + (jj >> 1)) : (jj >> 1);
    const float4* s = (const float4*)(fc1 + (size_t)srow * 512 + col);
    float4 a = s[0], b = s[1];
    union { f16 h[8]; uint4 u; } pk;
    pk.h[0] = (f16)a.x; pk.h[1] = (f16)a.y; pk.h[2] = (f16)a.z; pk.h[3] = (f16)a.w;
    pk.h[4] = (f16)b.x; pk.h[5] = (f16)b.y; pk.h[6] = (f16)b.z; pk.h[7] = (f16)b.w;
    *(uint4*)(Wf1 + (size_t)jj * 512 + col) = pk.u;
  } else {                             // fc2 straight copy (already [o][j])
    int q0 = blk - 3264;
    size_t e = ((size_t)q0 * 256 + tid) * 8;
    const float4* s = (const float4*)(fc2 + e);
    float4 a = s[0], b = s[1];
    union { f16 h[8]; uint4 u; } pk;
    pk.h[0] = (f16)a.x; pk.h[1] = (f16)a.y; pk.h[2] = (f16)a.z; pk.h[3] = (f16)a.w;
    pk.h[4] = (f16)b.x; pk.h[5] = (f16)b.y; pk.h[6] = (f16)b.z; pk.h[7] = (f16)b.w;
    *(uint4*)(Wf2 + e) = pk.u;
  }
}

// ---------------- rmsnorm (writes f32 h and zero-padded fp16 hb2) ----------------
__global__ void k_rmsnorm(const float* __restrict__ x, const float* __restrict__ w,
                          float* __restrict__ h, f16* __restrict__ hb2) {
  int tid = threadIdx.x, l = tid & 63, wv = tid >> 6;
  int r = blockIdx.x * 4 + wv;
  int b = r >> 10, t = r & 1023;
  const float* xr = x + (size_t)r * 512;
  f16* hr = hb2 + (size_t)(b * 1026 + 2 + t) * 512;
  float v[8]; float ss = 0.f;
#pragma unroll
  for (int j = 0; j < 8; ++j) { v[j] = xr[j * 64 + l]; ss += v[j] * v[j]; }
#pragma unroll
  for (int o = 32; o; o >>= 1) ss += __shfl_xor(ss, o, 64);
  float rn = rsqrtf(ss * (1.f / 512.f) + 1e-5f);
#pragma unroll
  for (int j = 0; j < 8; ++j) {
    float hv = v[j] * rn * w[j * 64 + l];
    h[(size_t)r * 512 + j * 64 + l] = hv;
    hr[j * 64 + l] = (f16)hv;
  }
}

// ---------------- forward FFT of h -> Xbf (fp16, rows (b, f, re/im)) ----------------
// 256 blocks: (b, 4-col group). Two packed complex FFTs per block.
__global__ void k_fft_fwd(const float* __restrict__ h, f16* __restrict__ Xbf,
                          const float2* __restrict__ tw) {
  __shared__ float2 z[2048];
  __shared__ __align__(16) f16 Xst[RPB * 4];
  int tid = threadIdx.x;
  int b = blockIdx.x >> 7;
  int dg4 = blockIdx.x & 127;
  for (int i = tid; i < 62 * 4; i += 256) Xst[(2050 + (i >> 2)) * 4 + (i & 3)] = (f16)0.f;
  for (int c4 = 0; c4 < 2; ++c4) {
    int d0 = dg4 * 4 + 2 * c4;
    __syncthreads();
    for (int t = tid; t < 1024; t += 256)
      z[t] = *(const float2*)(h + (size_t)(b * 1024 + t) * 512 + d0);
    for (int t = 1024 + tid; t < 2048; t += 256) z[t] = mkf2(0.f, 0.f);
    __syncthreads();
    fft2048<false>(z, tw, tid);
    for (int f = tid; f <= 1024; f += 256) {
      float2 zf = z[f], zc = z[(2048 - f) & 2047];
      float x0r = 0.5f * (zf.x + zc.x), x0i = 0.5f * (zf.y - zc.y);
      float x1r = 0.5f * (zf.y + zc.y), x1i = 0.5f * (zc.x - zf.x);
      Xst[(2 * f) * 4 + 2 * c4]         = (f16)x0r;
      Xst[(2 * f + 1) * 4 + 2 * c4]     = (f16)x0i;
      Xst[(2 * f) * 4 + 2 * c4 + 1]     = (f16)x1r;
      Xst[(2 * f + 1) * 4 + 2 * c4 + 1] = (f16)x1i;
    }
  }
  __syncthreads();
  for (int i = tid; i < RPB; i += 256)
    *(uint2*)(Xbf + (size_t)(b * RPB + i) * 512 + dg4 * 4) = *(const uint2*)&Xst[i * 4];
}

// ---------------- inverse FFT: sum of NPART f16 partials -> spec ----------------
// 256 blocks: (b, 4-o group). Two packed complex iFFTs per block.
__global__ void k_fft_inv(const f16* __restrict__ P, float* __restrict__ spec,
                          const float2* __restrict__ tw) {
  __shared__ float2 z[2048];
  __shared__ __align__(16) float Sst[1024 * 4];
  int tid = threadIdx.x;
  int b = blockIdx.x >> 7;
  int og4 = blockIdx.x & 127;
  for (int c4 = 0; c4 < 2; ++c4) {
    int o0 = og4 * 4 + 2 * c4;
    __syncthreads();
    for (int f = tid; f <= 1024; f += 256) {
      size_t base0 = (size_t)o0 * RTOT + (size_t)b * RPB + 2 * f;
      float s0r = 0.f, s0i = 0.f, s1r = 0.f, s1i = 0.f;
#pragma unroll
      for (int g = 0; g < NPART; ++g) {
        const f16* Pg = P + (size_t)g * 512 * RTOT;
        union { unsigned u; f16 h[2]; } ua, uc;
        ua.u = *(const unsigned*)(Pg + base0);
        uc.u = *(const unsigned*)(Pg + base0 + RTOT);
        s0r += (float)ua.h[0]; s0i += (float)ua.h[1];
        s1r += (float)uc.h[0]; s1i += (float)uc.h[1];
      }
      z[f] = mkf2(s0r - s1i, s0i + s1r);
      if (f >= 1 && f <= 1023) z[2048 - f] = mkf2(s0r + s1i, s1r - s0i);
    }
    __syncthreads();
    fft2048<true>(z, tw, tid);
    for (int t = tid; t < 1024; t += 256) {
      Sst[t * 4 + 2 * c4]     = z[t].x;
      Sst[t * 4 + 2 * c4 + 1] = z[t].y;
    }
  }
  __syncthreads();
  for (int i = tid; i < 1024; i += 256)
    *(float4*)(spec + (size_t)(b * 1024 + i) * 512 + og4 * 4) = *(const float4*)&Sst[i * 4];
}

// ---------------- unified MFMA GEMM, 1-deep counted-vmcnt pipeline ----------------
// Tiles BM=MR*32 x BN=NR*32, BK=64, 4 waves, double-buffered LDS.
// Staging: global_load_lds 16B/lane, LDS linear [rows][64] f16, XOR swizzle (chunk ^= row&7)
// baked into the per-lane GLOBAL source address; read side uses the matching XOR.
// MODE 0: spectral  C-rows=(b,f,c) A=Xbf   C-cols=o  B=Wsp (kb loop, complex-scale) -> P[bz] f16
// MODE 1: AR        C-rows=o       A=Wu    C-cols=r  B=hb2 (padded window)  -> x1 = x+spec+acc
// MODE 2: MLP1      C-rows=jj      A=fc1p  C-cols=r  B=x1b                  -> g1 = y*silu(gate)
// MODE 3: MLP2      C-rows=o       A=fc2   C-cols=r  B=g1                   -> x = x + x1 + acc
template<int MODE, int MR, int NR>
__device__ __forceinline__ void stage(const f16* __restrict__ A, const f16* __restrict__ B0,
                                      int r0, int c0, int bz, int tid, int s,
                                      f16* As, f16* Bs) {
  constexpr int LDA = (MODE == 0) ? 512 : (MODE == 1) ? 1536 : (MODE == 2) ? 512 : 2048;
  const int kA = (MODE == 0) ? ((s & 7) * 64) : s * 64;
  const int rowl = tid >> 3;
  const int lc8 = ((tid & 7) ^ (rowl & 7)) * 8;   // swizzled chunk * 8 (f16)
  f16* lA = As + ((tid >> 6) << 9);               // wave-uniform LDS base
  f16* lB = Bs + ((tid >> 6) << 9);
#pragma unroll
  for (int i = 0; i < MR; ++i) {
    int row = i * 32 + rowl;
    gl16(A + (size_t)(r0 + row) * LDA + kA + lc8, lA + i * 2048);
  }
#pragma unroll
  for (int i = 0; i < NR; ++i) {
    int row = i * 32 + rowl;
    const f16* bs;
    if constexpr (MODE == 0) {
      int kb = bz * 4 + (s >> 3);
      bs = B0 + (size_t)(kb * 512 + c0 + row) * 512 + (s & 7) * 64 + lc8;
    } else if constexpr (MODE == 1) {
      int ip = s >> 3, d0 = (s & 7) * 64;
      int rr = c0 + row;
      int b = rr >> 10, t = rr & 1023;
      bs = B0 + (size_t)(b * 1026 + t + ip) * 512 + d0 + lc8;   // pad rows are zero
    } else {
      constexpr int LDB = (MODE == 2) ? 512 : 2048;
      bs = B0 + (size_t)(c0 + row) * LDB + s * 64 + lc8;
    }
    gl16(bs, lB + i * 2048);
  }
}

template<int MR, int NR>
__device__ __forceinline__ void mma_step(const f16* As, const f16* Bs, int l, int wr, int wc,
                                         f32x4 acc[MR][NR]) {
  const int lr = l & 15, kg = l >> 4, sw = l & 7;
#pragma unroll
  for (int kk = 0; kk < 2; ++kk) {
    half8 af[MR], bf[NR];
    const int pc8 = (((kk * 4 + kg) ^ sw) << 3);
#pragma unroll
    for (int m = 0; m < MR; ++m)
      af[m] = *(const half8*)(As + (wr * (MR * 16) + m * 16 + lr) * 64 + pc8);
#pragma unroll
    for (int n = 0; n < NR; ++n)
      bf[n] = *(const half8*)(Bs + (wc * (NR * 16) + n * 16 + lr) * 64 + pc8);
#pragma unroll
    for (int m = 0; m < MR; ++m)
#pragma unroll
      for (int n = 0; n < NR; ++n)
        acc[m][n] = __builtin_amdgcn_mfma_f32_16x16x32_f16(af[m], bf[n], acc[m][n], 0, 0, 0);
  }
}

template<int MODE, int MR, int NR>
__global__ __launch_bounds__(256, (MODE == 0 || MODE == 2) ? 2 : 4)
void k_gemm(const f16* __restrict__ A, const f16* __restrict__ B0,
            const float* __restrict__ aux0, const float* aux1, const float* aux2,
            float* out1, f16* __restrict__ out2) {
  constexpr int ASZ = MR * 32 * 64, BSZ = NR * 32 * 64;
  __shared__ __align__(16) f16 As[2 * ASZ];
  __shared__ __align__(16) f16 Bs[2 * BSZ];
  const int tid = threadIdx.x, l = tid & 63, wvi = tid >> 6;
  const int wr = wvi >> 1, wc = wvi & 1;
  int bx, by, bz;
  if constexpr (MODE == 0) {           // 1D grid of 1056, XCD chunk swizzle (1056 = 8*132)
    int wg = (int)blockIdx.x;
    wg = (wg & 7) * 132 + (wg >> 3);
    bz = wg / 132; int rem = wg - bz * 132;
    by = rem >> 2; bx = rem & 3;
  } else { bx = blockIdx.x; by = blockIdx.y; bz = 0; }
  const int r0 = by * (MR * 32), c0 = bx * (NR * 32);
  constexpr int KS = (MODE == 0) ? 32 : (MODE == 1) ? 24 : (MODE == 2) ? 8 : 32;

  f32x4 acc[MR][NR];
  f32x4 crun[MR][NR];
  f32x4 zz = {0.f, 0.f, 0.f, 0.f};
#pragma unroll
  for (int m = 0; m < MR; ++m)
#pragma unroll
    for (int n = 0; n < NR; ++n) { acc[m][n] = zz; crun[m][n] = zz; }

  float4 csr[MR];                      // MODE 0: complex scales, loaded 7 steps early
  int f2_m[MR];
  if constexpr (MODE == 0) {
#pragma unroll
    for (int m = 0; m < MR; ++m) {
      int R = r0 + wr * (MR * 16) + m * 16 + ((l >> 4) << 2);
      int rb = (R >= RPB) ? R - RPB : R;
      f2_m[m] = (rb >> 1) * 2;
    }
  }

  stage<MODE, MR, NR>(A, B0, r0, c0, bz, tid, 0, As, Bs);
  for (int s = 0; s < KS; ++s) {
    const f16* Ac = As + (s & 1) * ASZ;
    const f16* Bc = Bs + (s & 1) * BSZ;
    if constexpr (MODE == 0) {
      if ((s & 7) == 0) {
        int kb = bz * 4 + (s >> 3);
#pragma unroll
        for (int m = 0; m < MR; ++m)
          csr[m] = *(const float4*)(aux0 + (size_t)kb * (CPS * 2) + f2_m[m]);
      }
    }
    if (s + 1 < KS) {
      stage<MODE, MR, NR>(A, B0, r0, c0, bz, tid, s + 1,
                          As + ((s + 1) & 1) * ASZ, Bs + ((s + 1) & 1) * BSZ);
      wait_vmcnt<MR + NR>();
    } else {
      wait_vmcnt<0>();
    }
    __builtin_amdgcn_s_barrier();
    __builtin_amdgcn_sched_barrier(0);
    mma_step<MR, NR>(Ac, Bc, l, wr, wc, acc);
    if constexpr (MODE == 0) {
      if ((s & 7) == 7) {
#pragma unroll
        for (int m = 0; m < MR; ++m) {
          float4 cs = csr[m];
#pragma unroll
          for (int n = 0; n < NR; ++n) {
            f32x4 p = acc[m][n];
            crun[m][n].x += cs.x * p.x - cs.y * p.y;
            crun[m][n].y += cs.x * p.y + cs.y * p.x;
            crun[m][n].z += cs.z * p.z - cs.w * p.w;
            crun[m][n].w += cs.z * p.w + cs.w * p.z;
            acc[m][n] = zz;
          }
        }
      }
    }
    asm volatile("s_waitcnt lgkmcnt(0)" ::: "memory");
    __builtin_amdgcn_s_barrier();
    __builtin_amdgcn_sched_barrier(0);
  }

  if constexpr (MODE == 0) {
    f16* P = out2 + (size_t)bz * (512ull * RTOT);
#pragma unroll
    for (int m = 0; m < MR; ++m) {
      int R0 = r0 + wr * (MR * 16) + m * 16 + ((l >> 4) << 2);
#pragma unroll
      for (int n = 0; n < NR; ++n) {
        int o = c0 + wc * (NR * 16) + n * 16 + (l & 15);
        union { f16 h[4]; uint2 u; } pk;
        pk.h[0] = (f16)crun[m][n].x; pk.h[1] = (f16)crun[m][n].y;
        pk.h[2] = (f16)crun[m][n].z; pk.h[3] = (f16)crun[m][n].w;
        *(uint2*)(P + (size_t)o * RTOT + R0) = pk.u;
      }
    }
  } else if constexpr (MODE == 1) {
#pragma unroll
    for (int m = 0; m < MR; ++m) {
      int o0 = r0 + wr * (MR * 16) + m * 16 + ((l >> 4) << 2);
#pragma unroll
      for (int n = 0; n < NR; ++n) {
        int r = c0 + wc * (NR * 16) + n * 16 + (l & 15);
        float4 xv = *(const float4*)(aux1 + (size_t)r * 512 + o0);
        float4 sv = *(const float4*)(aux2 + (size_t)r * 512 + o0);
        f32x4 a = acc[m][n];
        float4 res = make_float4(xv.x + sv.x + a.x, xv.y + sv.y + a.y,
                                 xv.z + sv.z + a.z, xv.w + sv.w + a.w);
        *(float4*)(out1 + (size_t)r * 512 + o0) = res;
        union { f16 h[4]; uint2 u; } pk;
        pk.h[0] = (f16)res.x; pk.h[1] = (f16)res.y; pk.h[2] = (f16)res.z; pk.h[3] = (f16)res.w;
        *(uint2*)(out2 + (size_t)r * 512 + o0) = pk.u;
      }
    }
  } else if constexpr (MODE == 2) {
#pragma unroll
    for (int m = 0; m < MR; ++m) {
      int jj0 = r0 + wr * (MR * 16) + m * 16 + ((l >> 4) << 2);
      int h2 = jj0 >> 1;
#pragma unroll
      for (int n = 0; n < NR; ++n) {
        int r = c0 + wc * (NR * 16) + n * 16 + (l & 15);
        f32x4 a = acc[m][n];
        float v0 = a.x * (a.y / (1.f + __expf(-a.y)));
        float v1 = a.z * (a.w / (1.f + __expf(-a.w)));
        union { f16 h[2]; unsigned u; } pk;
        pk.h[0] = (f16)v0; pk.h[1] = (f16)v1;
        *(unsigned*)(out2 + (size_t)r * 2048 + h2) = pk.u;
      }
    }
  } else {
#pragma unroll
    for (int m = 0; m < MR; ++m) {
      int o0 = r0 + wr * (MR * 16) + m * 16 + ((l >> 4) << 2);
#pragma unroll
      for (int n = 0; n < NR; ++n) {
        int r = c0 + wc * (NR * 16) + n * 16 + (l & 15);
        float4 xv  = *(const float4*)(aux1 + (size_t)r * 512 + o0);
        float4 x1v = *(const float4*)(aux2 + (size_t)r * 512 + o0);
        f32x4 a = acc[m][n];
        float4 res = make_float4(xv.x + x1v.x + a.x, xv.y + x1v.y + a.y,
                                 xv.z + x1v.z + a.z, xv.w + x1v.w + a.w);
        *(float4*)(out1 + (size_t)r * 512 + o0) = res;
      }
    }
  }
}

// ---------------- small projections ----------------
__global__ void k_inproj(const float* __restrict__ inp, const float* __restrict__ W,
                         float* __restrict__ x) {
  __shared__ float row[64];
  int r = blockIdx.x, tid = threadIdx.x;
  if (tid < 64) row[tid] = inp[(size_t)r * 64 + tid];
  __syncthreads();
  for (int o = tid; o < 512; o += 256) {
    const float* wr = W + (size_t)o * 64;
    float acc = 0.f;
#pragma unroll 8
    for (int q = 0; q < 64; ++q) acc += row[q] * wr[q];
    x[(size_t)r * 512 + o] = acc;
  }
}

__global__ void k_outproj(const float* __restrict__ x, const float* __restrict__ W,
                          float* out, int add) {
  __shared__ float row[512];
  int r = blockIdx.x, tid = threadIdx.x;
  for (int i = tid; i < 512; i += 64) row[i] = x[(size_t)r * 512 + i];
  __syncthreads();
  const float* wr = W + (size_t)tid * 512;
  float acc = 0.f;
  for (int q = 0; q < 512; ++q) acc += row[q] * wr[q];
  if (add) out[(size_t)r * 64 + tid] += acc;
  else     out[(size_t)r * 64 + tid] = acc;
}

// ---------------- host ----------------
extern "C" void kernel_launch(void* const* d_in, const int* in_sizes, int n_in,
                              void* d_out, int out_size, void* d_ws, size_t ws_size,
                              hipStream_t stream) {
  const float* inputs    = (const float*)d_in[0];
  const float* sigma     = (const float*)d_in[1];
  const float* phi       = (const float*)d_in[2];
  const float* in_proj_w = (const float*)d_in[3];
  const float* rn_w      = (const float*)d_in[4];
  const float* M_u       = (const float*)d_in[5];
  const float* M_phi_p   = (const float*)d_in[6];
  const float* M_phi_m   = (const float*)d_in[7];
  const float* fc1       = (const float*)d_in[8];
  const float* fc2       = (const float*)d_in[9];
  const float* out_proj_w= (const float*)d_in[10];
  float* out = (float*)d_out;

  char* ws = (char*)d_ws;
  size_t off = 0;
  auto alloc = [&](size_t bytes) -> void* {
    void* p = ws + off;
    off += (bytes + 255) & ~(size_t)255;
    return p;
  };
  float2* tw   = (float2*)alloc(1024 * 8);
  float2* Vf   = (float2*)alloc((size_t)16 * 1025 * 8);
  float2* cpcm = (float2*)alloc((size_t)32 * CPS * 8);
  float*  x    = (float*)alloc((size_t)NROW * 512 * 4);
  float*  h    = (float*)alloc((size_t)NROW * 512 * 4);
  f16*    hb2  = (f16*)alloc((size_t)2052 * 512 * 2);   // 2 batches x (2 pad + 1024) rows
  float*  x1   = (float*)alloc((size_t)NROW * 512 * 4);
  f16*    x1b  = (f16*)alloc((size_t)NROW * 512 * 2);
  float*  spec = (float*)alloc((size_t)NROW * 512 * 4);
  f16*    Xbf  = (f16*)alloc((size_t)RTOT * 512 * 2);
  f16*    P    = (f16*)alloc((size_t)NPART * 512 * RTOT * 2);
  f16*    g1   = (f16*)alloc((size_t)NROW * 2048 * 2);
  f16*    Wsp  = (f16*)alloc((size_t)16384 * 512 * 2);
  f16*    Wu   = (f16*)alloc((size_t)512 * 1536 * 2);
  f16*    Wf1  = (f16*)alloc((size_t)4096 * 512 * 2);
  f16*    Wf2  = (f16*)alloc((size_t)512 * 2048 * 2);
  if (off > ws_size) return;  // workspace too small: fail loudly (output stays poisoned)

  // zero the AR window pad rows (rows 0,1 of each batch block in hb2)
  hipMemsetAsync(hb2, 0, 2 * 512 * sizeof(f16), stream);
  hipMemsetAsync(hb2 + (size_t)1026 * 512, 0, 2 * 512 * sizeof(f16), stream);
  k_twiddle<<<4, 256, 0, stream>>>(tw);
  k_fft_phi<<<8, 256, 0, stream>>>(phi, Vf, tw);
  k_cpcm<<<133, 256, 0, stream>>>(Vf, sigma, cpcm);

  for (int m = 0; m < 2; ++m) {
    k_inproj<<<NROW, 256, 0, stream>>>(inputs, in_proj_w + (size_t)m * 512 * 64, x);
    for (int li = 0; li < 2; ++li) {
      int ml = m * 2 + li;
      k_cast<<<3776, 256, 0, stream>>>(
          M_phi_p + (size_t)ml * 16 * 262144, M_phi_m + (size_t)ml * 16 * 262144,
          M_u + (size_t)ml * 3 * 262144, fc1 + (size_t)ml * 4096 * 512,
          fc2 + (size_t)ml * 512 * 2048, Wsp, Wu, Wf1, Wf2);
      k_rmsnorm<<<512, 256, 0, stream>>>(x, rn_w + (size_t)ml * 512, h, hb2);
      k_fft_fwd<<<256, 256, 0, stream>>>(h, Xbf, tw);
      k_gemm<0, 4, 4><<<dim3(1056), 256, 0, stream>>>(Xbf, Wsp, (const float*)cpcm,
                                                      nullptr, nullptr, nullptr, P);
      k_fft_inv<<<256, 256, 0, stream>>>(P, spec, tw);
      k_gemm<1, 2, 2><<<dim3(32, 8), 256, 0, stream>>>(Wu, hb2, nullptr,
                                                       x, spec, x1, x1b);
      k_gemm<2, 4, 4><<<dim3(16, 32), 256, 0, stream>>>(Wf1, x1b, nullptr,
                                                        nullptr, nullptr, nullptr, g1);
      k_gemm<3, 2, 2><<<dim3(32, 8), 256, 0, stream>>>(Wf2, g1, nullptr,
                                                       x, x1, x, nullptr);
    }
    k_outproj<<<NROW, 64, 0, stream>>>(x, out_proj_w + (size_t)m * 64 * 512, out, m);
  }
}